// Round 1
// baseline (4438.871 us; speedup 1.0000x reference)
//
#include <hip/hip_runtime.h>
#include <hip/hip_bf16.h>

#define N_NODES 50000
#define N_EDGES 800000
#define D 128
#define L_LAYERS 3
#define BN_EPS 1e-5f

// ---------------------------------------------------------------------------
// Detect whether edge_index arrived as int64 (little-endian: odd int32 words
// are the high halves, all zero for values < 2^31) or as int32.
__global__ void detect_i64_kernel(const int* __restrict__ ei32, int* __restrict__ flag) {
    __shared__ int nz;
    if (threadIdx.x == 0) nz = 0;
    __syncthreads();
    int v = ei32[2 * threadIdx.x + 1];   // max idx 511 < 1.6M, safe either way
    if (v != 0) atomicAdd(&nz, 1);
    __syncthreads();
    if (threadIdx.x == 0) *flag = (nz == 0) ? 1 : 0;
}

// ---------------------------------------------------------------------------
// agg[dst] += x[src]  -- 32 threads per edge, float4 per thread, HW f32 atomics
__global__ __launch_bounds__(256) void scatter_kernel(const float* __restrict__ x,
        const void* __restrict__ ei, const int* __restrict__ flag64,
        float* __restrict__ agg) {
    int e = blockIdx.x * 8 + (threadIdx.x >> 5);
    int c = (threadIdx.x & 31) * 4;
    long long src, dst;
    if (*flag64) {
        const long long* p = (const long long*)ei;
        src = p[e]; dst = p[N_EDGES + e];
    } else {
        const int* p = (const int*)ei;
        src = (long long)p[e]; dst = (long long)p[N_EDGES + e];
    }
    float4 v = *(const float4*)(x + src * D + c);
    float* d = agg + dst * D + c;
    unsafeAtomicAdd(d + 0, v.x);
    unsafeAtomicAdd(d + 1, v.y);
    unsafeAtomicAdd(d + 2, v.z);
    unsafeAtomicAdd(d + 3, v.w);
}

// ---------------------------------------------------------------------------
// out = l2norm(agg) + (1+eps) * l2norm(x)   -- one wave (64 lanes) per row
__global__ __launch_bounds__(256) void prep_kernel(const float* __restrict__ agg,
        const float* __restrict__ x, const float* __restrict__ epsArr, int layer,
        float* __restrict__ out) {
    int row = blockIdx.x * 4 + (threadIdx.x >> 6);
    int lane = threadIdx.x & 63;
    const float2 a  = *(const float2*)(agg + (long long)row * D + lane * 2);
    const float2 xv = *(const float2*)(x   + (long long)row * D + lane * 2);
    float sa = a.x * a.x + a.y * a.y;
    float sx = xv.x * xv.x + xv.y * xv.y;
    #pragma unroll
    for (int m = 32; m >= 1; m >>= 1) {
        sa += __shfl_xor(sa, m);
        sx += __shfl_xor(sx, m);
    }
    float ra = 1.0f / fmaxf(sqrtf(sa), 1e-12f);
    float rx = (1.0f + epsArr[layer]) / fmaxf(sqrtf(sx), 1e-12f);
    float2 o;
    o.x = a.x * ra + xv.x * rx;
    o.y = a.y * ra + xv.y * rx;
    *(float2*)(out + (long long)row * D + lane * 2) = o;
}

// ---------------------------------------------------------------------------
// H = A @ W + b, plus per-column sum / sum-of-squares accumulation for BN.
// Block: 256 threads, 64-row tile. Thread (rg,cg): 8 rows x 4 cols register acc.
__global__ __launch_bounds__(256) void gemm_bn_stats_kernel(const float* __restrict__ A,
        const float* __restrict__ W, const float* __restrict__ b,
        float* __restrict__ Hout, float* __restrict__ gsum, float* __restrict__ gsq) {
    __shared__ float As[64 * D];
    __shared__ float lsum[D];
    __shared__ float lsq[D];
    int r0 = blockIdx.x * 64;
    for (int i = threadIdx.x; i < 64 * D / 4; i += 256) {
        int idx = i * 4;
        int rr = idx >> 7;
        int cc = idx & (D - 1);
        float4 v = make_float4(0.f, 0.f, 0.f, 0.f);
        if (r0 + rr < N_NODES) v = *(const float4*)(A + (long long)(r0 + rr) * D + cc);
        *(float4*)(As + idx) = v;
    }
    if (threadIdx.x < D) { lsum[threadIdx.x] = 0.f; lsq[threadIdx.x] = 0.f; }
    __syncthreads();

    int cg = threadIdx.x & 31;
    int rg = threadIdx.x >> 5;
    int c = cg * 4;
    float acc[8][4];
    #pragma unroll
    for (int j = 0; j < 8; j++) { acc[j][0] = acc[j][1] = acc[j][2] = acc[j][3] = 0.f; }

    #pragma unroll 4
    for (int k = 0; k < D; k++) {
        float4 w = *(const float4*)(W + k * D + c);
        #pragma unroll
        for (int j = 0; j < 8; j++) {
            float a = As[(rg * 8 + j) * D + k];
            acc[j][0] += a * w.x;
            acc[j][1] += a * w.y;
            acc[j][2] += a * w.z;
            acc[j][3] += a * w.w;
        }
    }

    float4 bb = *(const float4*)(b + c);
    float ps0 = 0, ps1 = 0, ps2 = 0, ps3 = 0;
    float pq0 = 0, pq1 = 0, pq2 = 0, pq3 = 0;
    #pragma unroll
    for (int j = 0; j < 8; j++) {
        int r = r0 + rg * 8 + j;
        if (r < N_NODES) {
            float4 hv;
            hv.x = acc[j][0] + bb.x;
            hv.y = acc[j][1] + bb.y;
            hv.z = acc[j][2] + bb.z;
            hv.w = acc[j][3] + bb.w;
            *(float4*)(Hout + (long long)r * D + c) = hv;
            ps0 += hv.x; ps1 += hv.y; ps2 += hv.z; ps3 += hv.w;
            pq0 += hv.x * hv.x; pq1 += hv.y * hv.y; pq2 += hv.z * hv.z; pq3 += hv.w * hv.w;
        }
    }
    atomicAdd(&lsum[c + 0], ps0);
    atomicAdd(&lsum[c + 1], ps1);
    atomicAdd(&lsum[c + 2], ps2);
    atomicAdd(&lsum[c + 3], ps3);
    atomicAdd(&lsq[c + 0], pq0);
    atomicAdd(&lsq[c + 1], pq1);
    atomicAdd(&lsq[c + 2], pq2);
    atomicAdd(&lsq[c + 3], pq3);
    __syncthreads();
    if (threadIdx.x < D) {
        atomicAdd(&gsum[threadIdx.x], lsum[threadIdx.x]);
        atomicAdd(&gsq[threadIdx.x], lsq[threadIdx.x]);
    }
}

// ---------------------------------------------------------------------------
__global__ void bn_finalize_kernel(const float* __restrict__ gsum, const float* __restrict__ gsq,
        const float* __restrict__ gamma, const float* __restrict__ beta,
        float* __restrict__ scale, float* __restrict__ shift) {
    int c = threadIdx.x;
    const float invN = 1.0f / (float)N_NODES;
    float mu = gsum[c] * invN;
    float var = fmaxf(gsq[c] * invN - mu * mu, 0.f);
    float is = rsqrtf(var + BN_EPS);
    float sc = gamma[c] * is;
    scale[c] = sc;
    shift[c] = beta[c] - mu * sc;
}

// ---------------------------------------------------------------------------
// Y = relu_opt( relu(scale*H + shift) @ W + b )
__global__ __launch_bounds__(256) void gemm_bn_apply_kernel(const float* __restrict__ H,
        const float* __restrict__ scale, const float* __restrict__ shift,
        const float* __restrict__ W, const float* __restrict__ b,
        float* __restrict__ Y, int reluOut) {
    __shared__ float As[64 * D];
    int r0 = blockIdx.x * 64;
    for (int i = threadIdx.x; i < 64 * D / 4; i += 256) {
        int idx = i * 4;
        int rr = idx >> 7;
        int cc = idx & (D - 1);
        float4 v = make_float4(0.f, 0.f, 0.f, 0.f);
        if (r0 + rr < N_NODES) {
            float4 hv = *(const float4*)(H + (long long)(r0 + rr) * D + cc);
            float4 sc = *(const float4*)(scale + cc);
            float4 sh = *(const float4*)(shift + cc);
            v.x = fmaxf(hv.x * sc.x + sh.x, 0.f);
            v.y = fmaxf(hv.y * sc.y + sh.y, 0.f);
            v.z = fmaxf(hv.z * sc.z + sh.z, 0.f);
            v.w = fmaxf(hv.w * sc.w + sh.w, 0.f);
        }
        *(float4*)(As + idx) = v;
    }
    __syncthreads();

    int cg = threadIdx.x & 31;
    int rg = threadIdx.x >> 5;
    int c = cg * 4;
    float acc[8][4];
    #pragma unroll
    for (int j = 0; j < 8; j++) { acc[j][0] = acc[j][1] = acc[j][2] = acc[j][3] = 0.f; }

    #pragma unroll 4
    for (int k = 0; k < D; k++) {
        float4 w = *(const float4*)(W + k * D + c);
        #pragma unroll
        for (int j = 0; j < 8; j++) {
            float a = As[(rg * 8 + j) * D + k];
            acc[j][0] += a * w.x;
            acc[j][1] += a * w.y;
            acc[j][2] += a * w.z;
            acc[j][3] += a * w.w;
        }
    }

    float4 bb = *(const float4*)(b + c);
    #pragma unroll
    for (int j = 0; j < 8; j++) {
        int r = r0 + rg * 8 + j;
        if (r < N_NODES) {
            float4 yv;
            yv.x = acc[j][0] + bb.x;
            yv.y = acc[j][1] + bb.y;
            yv.z = acc[j][2] + bb.z;
            yv.w = acc[j][3] + bb.w;
            if (reluOut) {
                yv.x = fmaxf(yv.x, 0.f);
                yv.y = fmaxf(yv.y, 0.f);
                yv.z = fmaxf(yv.z, 0.f);
                yv.w = fmaxf(yv.w, 0.f);
            }
            *(float4*)(Y + (long long)r * D + c) = yv;
        }
    }
}

// ---------------------------------------------------------------------------
extern "C" void kernel_launch(void* const* d_in, const int* in_sizes, int n_in,
                              void* d_out, int out_size, void* d_ws, size_t ws_size,
                              hipStream_t stream) {
    const float* x      = (const float*)d_in[0];
    const void*  ei     = d_in[1];
    const float* W1     = (const float*)d_in[2];
    const float* b1     = (const float*)d_in[3];
    const float* gamma  = (const float*)d_in[4];
    const float* beta   = (const float*)d_in[5];
    const float* W2     = (const float*)d_in[6];
    const float* b2     = (const float*)d_in[7];
    const float* epsArr = (const float*)d_in[8];
    float* out = (float*)d_out;

    char* ws = (char*)d_ws;
    const size_t bufBytes = (size_t)N_NODES * D * sizeof(float);
    float* Bagg  = (float*)ws;                    // agg, then reused as h
    float* Bout  = (float*)(ws + bufBytes);       // combined pre-MLP features
    float* Bx    = (float*)(ws + 2 * bufBytes);   // layer output / next x
    float* gsum  = (float*)(ws + 3 * bufBytes);
    float* gsq   = gsum + D;
    float* scale = gsum + 2 * D;
    float* shift = gsum + 3 * D;
    int*   flag  = (int*)(gsum + 4 * D);

    detect_i64_kernel<<<1, 256, 0, stream>>>((const int*)ei, flag);

    for (int l = 0; l < L_LAYERS; l++) {
        const float* xin = (l == 0) ? x : Bx;
        float* yout = (l == L_LAYERS - 1) ? out : Bx;

        hipMemsetAsync(Bagg, 0, bufBytes, stream);
        hipMemsetAsync(gsum, 0, 2 * D * sizeof(float), stream);

        scatter_kernel<<<N_EDGES / 8, 256, 0, stream>>>(xin, ei, flag, Bagg);
        prep_kernel<<<N_NODES / 4, 256, 0, stream>>>(Bagg, xin, epsArr, l, Bout);
        gemm_bn_stats_kernel<<<(N_NODES + 63) / 64, 256, 0, stream>>>(
            Bout, W1 + (size_t)l * D * D, b1 + (size_t)l * D, Bagg, gsum, gsq);
        bn_finalize_kernel<<<1, D, 0, stream>>>(gsum, gsq, gamma + (size_t)l * D,
                                                beta + (size_t)l * D, scale, shift);
        gemm_bn_apply_kernel<<<(N_NODES + 63) / 64, 256, 0, stream>>>(
            Bagg, scale, shift, W2 + (size_t)l * D * D, b2 + (size_t)l * D,
            yout, (l != L_LAYERS - 1) ? 1 : 0);
    }
}

// Round 2
// 818.228 us; speedup vs baseline: 5.4250x; 5.4250x over previous
//
#include <hip/hip_runtime.h>
#include <hip/hip_bf16.h>

#define N_NODES 50000
#define N_EDGES 800000
#define D 128
#define L_LAYERS 3
#define BN_EPS 1e-5f
#define SCAN_CHUNK 196   // 196*256 = 50176 >= 50000

// ---------------------------------------------------------------------------
// Detect whether edge_index arrived as int64 (odd int32 words all zero) or int32.
__global__ void detect_i64_kernel(const int* __restrict__ ei32, int* __restrict__ flag) {
    __shared__ int nz;
    if (threadIdx.x == 0) nz = 0;
    __syncthreads();
    int v = ei32[2 * threadIdx.x + 1];
    if (v != 0) atomicAdd(&nz, 1);
    __syncthreads();
    if (threadIdx.x == 0) *flag = (nz == 0) ? 1 : 0;
}

__device__ __forceinline__ int edge_at(const void* ei, const int* flag64, long long i) {
    if (*flag64) return (int)((const long long*)ei)[i];
    return ((const int*)ei)[i];
}

// ---------------------------------------------------------------------------
// CSR build step 1: in-degree histogram over dst.
__global__ __launch_bounds__(256) void degree_kernel(const void* __restrict__ ei,
        const int* __restrict__ flag64, int* __restrict__ deg) {
    int e = blockIdx.x * 256 + threadIdx.x;
    if (e >= N_EDGES) return;
    int dst = edge_at(ei, flag64, (long long)N_EDGES + e);
    atomicAdd(&deg[dst], 1);
}

// CSR build step 2: exclusive scan of deg -> rowptr, copy to cursor. One block.
__global__ __launch_bounds__(256) void scan_kernel(const int* __restrict__ deg,
        int* __restrict__ rowptr, int* __restrict__ cursor) {
    __shared__ int sums[256];
    int t = threadIdx.x;
    int start = t * SCAN_CHUNK;
    int end = min(start + SCAN_CHUNK, N_NODES);
    int s = 0;
    for (int i = start; i < end; i++) s += deg[i];
    sums[t] = s;
    __syncthreads();
    // Hillis-Steele inclusive scan in LDS
    for (int off = 1; off < 256; off <<= 1) {
        int v = (t >= off) ? sums[t - off] : 0;
        __syncthreads();
        sums[t] += v;
        __syncthreads();
    }
    int prefix = (t == 0) ? 0 : sums[t - 1];   // exclusive
    for (int i = start; i < end; i++) {
        rowptr[i] = prefix;
        cursor[i] = prefix;
        prefix += deg[i];
    }
    if (t == 255) rowptr[N_NODES] = prefix;
}

// CSR build step 3: fill neighbor (src) lists via per-node cursors.
__global__ __launch_bounds__(256) void fill_kernel(const void* __restrict__ ei,
        const int* __restrict__ flag64, int* __restrict__ cursor, int* __restrict__ csr) {
    int e = blockIdx.x * 256 + threadIdx.x;
    if (e >= N_EDGES) return;
    int src = edge_at(ei, flag64, e);
    int dst = edge_at(ei, flag64, (long long)N_EDGES + e);
    int pos = atomicAdd(&cursor[dst], 1);
    csr[pos] = src;
}

// ---------------------------------------------------------------------------
// Per node: agg = sum_{j in N(i)} x[j];  out = l2norm(agg) + (1+eps)*l2norm(x_i)
// One wave per node, each lane owns 2 columns (float2).
__global__ __launch_bounds__(256) void gather_prep_kernel(const float* __restrict__ x,
        const int* __restrict__ rowptr, const int* __restrict__ csr,
        const float* __restrict__ epsArr, int layer, float* __restrict__ out) {
    int row = blockIdx.x * 4 + (threadIdx.x >> 6);
    if (row >= N_NODES) return;
    int lane = threadIdx.x & 63;
    int beg = rowptr[row], end = rowptr[row + 1];

    float2 acc0 = make_float2(0.f, 0.f);
    float2 acc1 = make_float2(0.f, 0.f);
    int j = beg;
    for (; j + 1 < end; j += 2) {
        int s0 = csr[j];
        int s1 = csr[j + 1];
        float2 v0 = *(const float2*)(x + (long long)s0 * D + lane * 2);
        float2 v1 = *(const float2*)(x + (long long)s1 * D + lane * 2);
        acc0.x += v0.x; acc0.y += v0.y;
        acc1.x += v1.x; acc1.y += v1.y;
    }
    if (j < end) {
        int s0 = csr[j];
        float2 v0 = *(const float2*)(x + (long long)s0 * D + lane * 2);
        acc0.x += v0.x; acc0.y += v0.y;
    }
    float2 a = make_float2(acc0.x + acc1.x, acc0.y + acc1.y);
    float2 xv = *(const float2*)(x + (long long)row * D + lane * 2);

    float sa = a.x * a.x + a.y * a.y;
    float sx = xv.x * xv.x + xv.y * xv.y;
    #pragma unroll
    for (int m = 32; m >= 1; m >>= 1) {
        sa += __shfl_xor(sa, m);
        sx += __shfl_xor(sx, m);
    }
    float ra = 1.0f / fmaxf(sqrtf(sa), 1e-12f);
    float rx = (1.0f + epsArr[layer]) / fmaxf(sqrtf(sx), 1e-12f);
    float2 o;
    o.x = a.x * ra + xv.x * rx;
    o.y = a.y * ra + xv.y * rx;
    *(float2*)(out + (long long)row * D + lane * 2) = o;
}

// ---------------------------------------------------------------------------
// H = A @ W + b, plus per-column sum / sum-of-squares accumulation for BN.
__global__ __launch_bounds__(256) void gemm_bn_stats_kernel(const float* __restrict__ A,
        const float* __restrict__ W, const float* __restrict__ b,
        float* __restrict__ Hout, float* __restrict__ gsum, float* __restrict__ gsq) {
    __shared__ float As[64 * D];
    __shared__ float lsum[D];
    __shared__ float lsq[D];
    int r0 = blockIdx.x * 64;
    for (int i = threadIdx.x; i < 64 * D / 4; i += 256) {
        int idx = i * 4;
        int rr = idx >> 7;
        int cc = idx & (D - 1);
        float4 v = make_float4(0.f, 0.f, 0.f, 0.f);
        if (r0 + rr < N_NODES) v = *(const float4*)(A + (long long)(r0 + rr) * D + cc);
        *(float4*)(As + idx) = v;
    }
    if (threadIdx.x < D) { lsum[threadIdx.x] = 0.f; lsq[threadIdx.x] = 0.f; }
    __syncthreads();

    int cg = threadIdx.x & 31;
    int rg = threadIdx.x >> 5;
    int c = cg * 4;
    float acc[8][4];
    #pragma unroll
    for (int j = 0; j < 8; j++) { acc[j][0] = acc[j][1] = acc[j][2] = acc[j][3] = 0.f; }

    #pragma unroll 4
    for (int k = 0; k < D; k++) {
        float4 w = *(const float4*)(W + k * D + c);
        #pragma unroll
        for (int j = 0; j < 8; j++) {
            float a = As[(rg * 8 + j) * D + k];
            acc[j][0] += a * w.x;
            acc[j][1] += a * w.y;
            acc[j][2] += a * w.z;
            acc[j][3] += a * w.w;
        }
    }

    float4 bb = *(const float4*)(b + c);
    float ps0 = 0, ps1 = 0, ps2 = 0, ps3 = 0;
    float pq0 = 0, pq1 = 0, pq2 = 0, pq3 = 0;
    #pragma unroll
    for (int j = 0; j < 8; j++) {
        int r = r0 + rg * 8 + j;
        if (r < N_NODES) {
            float4 hv;
            hv.x = acc[j][0] + bb.x;
            hv.y = acc[j][1] + bb.y;
            hv.z = acc[j][2] + bb.z;
            hv.w = acc[j][3] + bb.w;
            *(float4*)(Hout + (long long)r * D + c) = hv;
            ps0 += hv.x; ps1 += hv.y; ps2 += hv.z; ps3 += hv.w;
            pq0 += hv.x * hv.x; pq1 += hv.y * hv.y; pq2 += hv.z * hv.z; pq3 += hv.w * hv.w;
        }
    }
    atomicAdd(&lsum[c + 0], ps0);
    atomicAdd(&lsum[c + 1], ps1);
    atomicAdd(&lsum[c + 2], ps2);
    atomicAdd(&lsum[c + 3], ps3);
    atomicAdd(&lsq[c + 0], pq0);
    atomicAdd(&lsq[c + 1], pq1);
    atomicAdd(&lsq[c + 2], pq2);
    atomicAdd(&lsq[c + 3], pq3);
    __syncthreads();
    if (threadIdx.x < D) {
        atomicAdd(&gsum[threadIdx.x], lsum[threadIdx.x]);
        atomicAdd(&gsq[threadIdx.x], lsq[threadIdx.x]);
    }
}

// ---------------------------------------------------------------------------
__global__ void bn_finalize_kernel(const float* __restrict__ gsum, const float* __restrict__ gsq,
        const float* __restrict__ gamma, const float* __restrict__ beta,
        float* __restrict__ scale, float* __restrict__ shift) {
    int c = threadIdx.x;
    const float invN = 1.0f / (float)N_NODES;
    float mu = gsum[c] * invN;
    float var = fmaxf(gsq[c] * invN - mu * mu, 0.f);
    float is = rsqrtf(var + BN_EPS);
    float sc = gamma[c] * is;
    scale[c] = sc;
    shift[c] = beta[c] - mu * sc;
}

// ---------------------------------------------------------------------------
// Y = relu_opt( relu(scale*H + shift) @ W + b )
__global__ __launch_bounds__(256) void gemm_bn_apply_kernel(const float* __restrict__ H,
        const float* __restrict__ scale, const float* __restrict__ shift,
        const float* __restrict__ W, const float* __restrict__ b,
        float* __restrict__ Y, int reluOut) {
    __shared__ float As[64 * D];
    int r0 = blockIdx.x * 64;
    for (int i = threadIdx.x; i < 64 * D / 4; i += 256) {
        int idx = i * 4;
        int rr = idx >> 7;
        int cc = idx & (D - 1);
        float4 v = make_float4(0.f, 0.f, 0.f, 0.f);
        if (r0 + rr < N_NODES) {
            float4 hv = *(const float4*)(H + (long long)(r0 + rr) * D + cc);
            float4 sc = *(const float4*)(scale + cc);
            float4 sh = *(const float4*)(shift + cc);
            v.x = fmaxf(hv.x * sc.x + sh.x, 0.f);
            v.y = fmaxf(hv.y * sc.y + sh.y, 0.f);
            v.z = fmaxf(hv.z * sc.z + sh.z, 0.f);
            v.w = fmaxf(hv.w * sc.w + sh.w, 0.f);
        }
        *(float4*)(As + idx) = v;
    }
    __syncthreads();

    int cg = threadIdx.x & 31;
    int rg = threadIdx.x >> 5;
    int c = cg * 4;
    float acc[8][4];
    #pragma unroll
    for (int j = 0; j < 8; j++) { acc[j][0] = acc[j][1] = acc[j][2] = acc[j][3] = 0.f; }

    #pragma unroll 4
    for (int k = 0; k < D; k++) {
        float4 w = *(const float4*)(W + k * D + c);
        #pragma unroll
        for (int j = 0; j < 8; j++) {
            float a = As[(rg * 8 + j) * D + k];
            acc[j][0] += a * w.x;
            acc[j][1] += a * w.y;
            acc[j][2] += a * w.z;
            acc[j][3] += a * w.w;
        }
    }

    float4 bb = *(const float4*)(b + c);
    #pragma unroll
    for (int j = 0; j < 8; j++) {
        int r = r0 + rg * 8 + j;
        if (r < N_NODES) {
            float4 yv;
            yv.x = acc[j][0] + bb.x;
            yv.y = acc[j][1] + bb.y;
            yv.z = acc[j][2] + bb.z;
            yv.w = acc[j][3] + bb.w;
            if (reluOut) {
                yv.x = fmaxf(yv.x, 0.f);
                yv.y = fmaxf(yv.y, 0.f);
                yv.z = fmaxf(yv.z, 0.f);
                yv.w = fmaxf(yv.w, 0.f);
            }
            *(float4*)(Y + (long long)r * D + c) = yv;
        }
    }
}

// ---------------------------------------------------------------------------
extern "C" void kernel_launch(void* const* d_in, const int* in_sizes, int n_in,
                              void* d_out, int out_size, void* d_ws, size_t ws_size,
                              hipStream_t stream) {
    const float* x      = (const float*)d_in[0];
    const void*  ei     = d_in[1];
    const float* W1     = (const float*)d_in[2];
    const float* b1     = (const float*)d_in[3];
    const float* gamma  = (const float*)d_in[4];
    const float* beta   = (const float*)d_in[5];
    const float* W2     = (const float*)d_in[6];
    const float* b2     = (const float*)d_in[7];
    const float* epsArr = (const float*)d_in[8];
    float* out = (float*)d_out;

    char* ws = (char*)d_ws;
    const size_t bufBytes = (size_t)N_NODES * D * sizeof(float);
    float* Bout  = (float*)ws;                    // combined pre-MLP features
    float* Bh    = (float*)(ws + bufBytes);       // GEMM1 output (pre-BN)
    float* Bx    = (float*)(ws + 2 * bufBytes);   // layer output / next x
    char*  p     = ws + 3 * bufBytes;
    int* rowptr  = (int*)p;              p += (N_NODES + 1) * sizeof(int);
    int* deg     = (int*)p;              p += N_NODES * sizeof(int);
    int* cursor  = (int*)p;              p += N_NODES * sizeof(int);
    int* csr     = (int*)p;              p += N_EDGES * sizeof(int);
    float* gsum  = (float*)p;            p += D * sizeof(float);
    float* gsq   = (float*)p;            p += D * sizeof(float);
    float* scale = (float*)p;            p += D * sizeof(float);
    float* shift = (float*)p;            p += D * sizeof(float);
    int* flag    = (int*)p;

    detect_i64_kernel<<<1, 256, 0, stream>>>((const int*)ei, flag);

    // Build CSR once; reused by all 3 layers.
    hipMemsetAsync(deg, 0, N_NODES * sizeof(int), stream);
    degree_kernel<<<(N_EDGES + 255) / 256, 256, 0, stream>>>(ei, flag, deg);
    scan_kernel<<<1, 256, 0, stream>>>(deg, rowptr, cursor);
    fill_kernel<<<(N_EDGES + 255) / 256, 256, 0, stream>>>(ei, flag, cursor, csr);

    for (int l = 0; l < L_LAYERS; l++) {
        const float* xin = (l == 0) ? x : Bx;
        float* yout = (l == L_LAYERS - 1) ? out : Bx;

        hipMemsetAsync(gsum, 0, 2 * D * sizeof(float), stream);

        gather_prep_kernel<<<(N_NODES + 3) / 4, 256, 0, stream>>>(
            xin, rowptr, csr, epsArr, l, Bout);
        gemm_bn_stats_kernel<<<(N_NODES + 63) / 64, 256, 0, stream>>>(
            Bout, W1 + (size_t)l * D * D, b1 + (size_t)l * D, Bh, gsum, gsq);
        bn_finalize_kernel<<<1, D, 0, stream>>>(gsum, gsq, gamma + (size_t)l * D,
                                                beta + (size_t)l * D, scale, shift);
        gemm_bn_apply_kernel<<<(N_NODES + 63) / 64, 256, 0, stream>>>(
            Bh, scale, shift, W2 + (size_t)l * D * D, b2 + (size_t)l * D,
            yout, (l != L_LAYERS - 1) ? 1 : 0);
    }
}

// Round 4
// 608.929 us; speedup vs baseline: 7.2896x; 1.3437x over previous
//
#include <hip/hip_runtime.h>
#include <hip/hip_bf16.h>

#define N_NODES 50000
#define N_EDGES 800000
#define D 128
#define L_LAYERS 3
#define BN_EPS 1e-5f
#define SCAN_BLOCKS 196   // 196*256 = 50176 >= 50000

typedef __attribute__((ext_vector_type(8))) short short8;
typedef __attribute__((ext_vector_type(4))) float floatx4;

__device__ __forceinline__ short f2bf(float f) {
    unsigned u = __builtin_bit_cast(unsigned, f);
    u += 0x7FFFu + ((u >> 16) & 1u);   // round-to-nearest-even
    return (short)(u >> 16);
}

// ---------------------------------------------------------------------------
// Detect whether edge_index arrived as int64 (odd int32 words all zero) or int32.
__global__ void detect_i64_kernel(const int* __restrict__ ei32, int* __restrict__ flag) {
    __shared__ int nz;
    if (threadIdx.x == 0) nz = 0;
    __syncthreads();
    int v = ei32[2 * threadIdx.x + 1];
    if (v != 0) atomicAdd(&nz, 1);
    __syncthreads();
    if (threadIdx.x == 0) *flag = (nz == 0) ? 1 : 0;
}

__device__ __forceinline__ int edge_at(const void* ei, const int* flag64, long long i) {
    if (*flag64) return (int)((const long long*)ei)[i];
    return ((const int*)ei)[i];
}

// ---------------------------------------------------------------------------
// CSR build step 1: in-degree histogram over dst.
__global__ __launch_bounds__(256) void degree_kernel(const void* __restrict__ ei,
        const int* __restrict__ flag64, int* __restrict__ deg) {
    int e = blockIdx.x * 256 + threadIdx.x;
    if (e >= N_EDGES) return;
    int dst = edge_at(ei, flag64, (long long)N_EDGES + e);
    atomicAdd(&deg[dst], 1);
}

// CSR build step 2a: per-block (256-elem) sums of deg.
__global__ __launch_bounds__(256) void blocksum_kernel(const int* __restrict__ deg,
        int* __restrict__ bsum) {
    int i = blockIdx.x * 256 + threadIdx.x;
    int v = (i < N_NODES) ? deg[i] : 0;
    #pragma unroll
    for (int m = 32; m >= 1; m >>= 1) v += __shfl_xor(v, m);
    __shared__ int ws_[4];
    if ((threadIdx.x & 63) == 0) ws_[threadIdx.x >> 6] = v;
    __syncthreads();
    if (threadIdx.x == 0) bsum[blockIdx.x] = ws_[0] + ws_[1] + ws_[2] + ws_[3];
}

// CSR build step 2b: exclusive scan of the 196 block sums (1 block).
__global__ __launch_bounds__(256) void scan_bsum_kernel(int* __restrict__ bsum) {
    __shared__ int s[256];
    int t = threadIdx.x;
    int v = (t < SCAN_BLOCKS) ? bsum[t] : 0;
    s[t] = v;
    __syncthreads();
    for (int off = 1; off < 256; off <<= 1) {
        int u = (t >= off) ? s[t - off] : 0;
        __syncthreads();
        s[t] += u;
        __syncthreads();
    }
    if (t < SCAN_BLOCKS) bsum[t] = s[t] - v;   // exclusive
}

// CSR build step 2c: per-block local scan + block offset -> rowptr, cursor.
__global__ __launch_bounds__(256) void rowptr_kernel(const int* __restrict__ deg,
        const int* __restrict__ bsum, int* __restrict__ rowptr, int* __restrict__ cursor) {
    __shared__ int s[256];
    int i = blockIdx.x * 256 + threadIdx.x;
    int v = (i < N_NODES) ? deg[i] : 0;
    s[threadIdx.x] = v;
    __syncthreads();
    for (int off = 1; off < 256; off <<= 1) {
        int u = (threadIdx.x >= off) ? s[threadIdx.x - off] : 0;
        __syncthreads();
        s[threadIdx.x] += u;
        __syncthreads();
    }
    int excl = s[threadIdx.x] - v + bsum[blockIdx.x];
    if (i < N_NODES) { rowptr[i] = excl; cursor[i] = excl; }
    if (i == N_NODES) rowptr[N_NODES] = N_EDGES;
}

// CSR build step 3: fill neighbor (src) lists via per-node cursors.
__global__ __launch_bounds__(256) void fill_kernel(const void* __restrict__ ei,
        const int* __restrict__ flag64, int* __restrict__ cursor, int* __restrict__ csr) {
    int e = blockIdx.x * 256 + threadIdx.x;
    if (e >= N_EDGES) return;
    int src = edge_at(ei, flag64, e);
    int dst = edge_at(ei, flag64, (long long)N_EDGES + e);
    int pos = atomicAdd(&cursor[dst], 1);
    csr[pos] = src;
}

// ---------------------------------------------------------------------------
// Pre-permute W (fp32 [k][n]) into bf16 MFMA B-fragment order:
// Wp[(((kt*8+nt)*64+lane)*8)+j] = bf16(W[(kt*32+(lane>>4)*8+j)*128 + nt*16+(lane&15)])
__global__ __launch_bounds__(256) void wperm_kernel(const float* __restrict__ W1,
        const float* __restrict__ W2, short* __restrict__ Wp) {
    int tid = blockIdx.x * 256 + threadIdx.x;   // 6*2048 total
    int mat = tid >> 11;
    int t2 = tid & 2047;
    int kt = t2 >> 9;
    int nt = (t2 >> 6) & 7;
    int lane = t2 & 63;
    const float* W = (mat < 3) ? (W1 + (size_t)mat * D * D)
                               : (W2 + (size_t)(mat - 3) * D * D);
    int kbase = kt * 32 + (lane >> 4) * 8;
    int n = nt * 16 + (lane & 15);
    short8 frag;
    #pragma unroll
    for (int j = 0; j < 8; j++) frag[j] = f2bf(W[(kbase + j) * D + n]);
    *(short8*)(Wp + (size_t)mat * D * D + (size_t)t2 * 8) = frag;
}

// ---------------------------------------------------------------------------
// Per node: agg = sum_{j in N(i)} x[j];  out = l2norm(agg) + (1+eps)*l2norm(x_i)
// One wave per node, each lane owns 2 columns. Output written as bf16 (packed).
__global__ __launch_bounds__(256) void gather_prep_kernel(const float* __restrict__ x,
        const int* __restrict__ rowptr, const int* __restrict__ csr,
        const float* __restrict__ epsArr, int layer, unsigned* __restrict__ out16) {
    int row = blockIdx.x * 4 + (threadIdx.x >> 6);
    if (row >= N_NODES) return;
    int lane = threadIdx.x & 63;
    int beg = rowptr[row], end = rowptr[row + 1];

    float2 acc0 = make_float2(0.f, 0.f);
    float2 acc1 = make_float2(0.f, 0.f);
    int j = beg;
    for (; j + 1 < end; j += 2) {
        int s0 = csr[j];
        int s1 = csr[j + 1];
        float2 v0 = *(const float2*)(x + (long long)s0 * D + lane * 2);
        float2 v1 = *(const float2*)(x + (long long)s1 * D + lane * 2);
        acc0.x += v0.x; acc0.y += v0.y;
        acc1.x += v1.x; acc1.y += v1.y;
    }
    if (j < end) {
        int s0 = csr[j];
        float2 v0 = *(const float2*)(x + (long long)s0 * D + lane * 2);
        acc0.x += v0.x; acc0.y += v0.y;
    }
    float2 a = make_float2(acc0.x + acc1.x, acc0.y + acc1.y);
    float2 xv = *(const float2*)(x + (long long)row * D + lane * 2);

    float sa = a.x * a.x + a.y * a.y;
    float sx = xv.x * xv.x + xv.y * xv.y;
    #pragma unroll
    for (int m = 32; m >= 1; m >>= 1) {
        sa += __shfl_xor(sa, m);
        sx += __shfl_xor(sx, m);
    }
    float ra = 1.0f / fmaxf(sqrtf(sa), 1e-12f);
    float rx = (1.0f + epsArr[layer]) / fmaxf(sqrtf(sx), 1e-12f);
    float ox = a.x * ra + xv.x * rx;
    float oy = a.y * ra + xv.y * rx;
    unsigned pack = (unsigned)(unsigned short)f2bf(ox)
                  | ((unsigned)(unsigned short)f2bf(oy) << 16);
    out16[(long long)row * 64 + lane] = pack;
}

// ---------------------------------------------------------------------------
// GEMM1 (MFMA bf16): H = A@W1 + b1 (fp32 out) + per-column BN stats.
__global__ __launch_bounds__(256) void gemm1_mfma_kernel(const short* __restrict__ Ab,
        const short* __restrict__ Wp, const float* __restrict__ b,
        float* __restrict__ Hout, float* __restrict__ gsum, float* __restrict__ gsq) {
    __shared__ float lsum[D];
    __shared__ float lsq[D];
    if (threadIdx.x < D) { lsum[threadIdx.x] = 0.f; lsq[threadIdx.x] = 0.f; }
    __syncthreads();

    int wave = threadIdx.x >> 6, lane = threadIdx.x & 63;
    int r0 = blockIdx.x * 64 + wave * 16;
    int m = lane & 15, g = lane >> 4;
    int arow = r0 + m;
    bool valid = arow < N_NODES;

    short8 a[4];
    #pragma unroll
    for (int kt = 0; kt < 4; kt++) {
        if (valid) {
            a[kt] = *(const short8*)(Ab + (long long)arow * D + kt * 32 + g * 8);
        } else {
            a[kt] = (short8)0;
        }
    }

    floatx4 acc[8];
    #pragma unroll
    for (int nt = 0; nt < 8; nt++) acc[nt] = (floatx4){0.f, 0.f, 0.f, 0.f};

    #pragma unroll
    for (int nt = 0; nt < 8; nt++) {
        #pragma unroll
        for (int kt = 0; kt < 4; kt++) {
            short8 bf = *(const short8*)(Wp + (size_t)((kt * 8 + nt) * 64 + lane) * 8);
            acc[nt] = __builtin_amdgcn_mfma_f32_16x16x32_bf16(a[kt], bf, acc[nt], 0, 0, 0);
        }
    }

    #pragma unroll
    for (int nt = 0; nt < 8; nt++) {
        int col = nt * 16 + m;
        float bcol = b[col];
        float s = 0.f, q = 0.f;
        #pragma unroll
        for (int r = 0; r < 4; r++) {
            int grow = r0 + g * 4 + r;
            if (grow < N_NODES) {
                float h = acc[nt][r] + bcol;
                Hout[(long long)grow * D + col] = h;
                s += h; q += h * h;
            }
        }
        s += __shfl_xor(s, 16); s += __shfl_xor(s, 32);
        q += __shfl_xor(q, 16); q += __shfl_xor(q, 32);
        if (lane < 16) {
            atomicAdd(&lsum[col], s);
            atomicAdd(&lsq[col], q);
        }
    }
    __syncthreads();
    if (threadIdx.x < D) {
        atomicAdd(&gsum[threadIdx.x], lsum[threadIdx.x]);
        atomicAdd(&gsq[threadIdx.x], lsq[threadIdx.x]);
    }
}

// ---------------------------------------------------------------------------
__global__ void bn_finalize_kernel(const float* __restrict__ gsum, const float* __restrict__ gsq,
        const float* __restrict__ gamma, const float* __restrict__ beta,
        float* __restrict__ scale, float* __restrict__ shift) {
    int c = threadIdx.x;
    const float invN = 1.0f / (float)N_NODES;
    float mu = gsum[c] * invN;
    float var = fmaxf(gsq[c] * invN - mu * mu, 0.f);
    float is = rsqrtf(var + BN_EPS);
    float sc = gamma[c] * is;
    scale[c] = sc;
    shift[c] = beta[c] - mu * sc;
}

// ---------------------------------------------------------------------------
// GEMM2 (MFMA bf16): Y = relu_opt( relu(scale*H+shift) @ W2 + b2 ), fp32 out.
__global__ __launch_bounds__(256) void gemm2_mfma_kernel(const float* __restrict__ H,
        const float* __restrict__ scale, const float* __restrict__ shift,
        const short* __restrict__ Wp, const float* __restrict__ b,
        float* __restrict__ Y, int reluOut) {
    int wave = threadIdx.x >> 6, lane = threadIdx.x & 63;
    int r0 = blockIdx.x * 64 + wave * 16;
    int m = lane & 15, g = lane >> 4;
    int arow = r0 + m;
    bool valid = arow < N_NODES;

    short8 a[4];
    #pragma unroll
    for (int kt = 0; kt < 4; kt++) {
        int koff = kt * 32 + g * 8;
        if (valid) {
            float4 h0 = *(const float4*)(H + (long long)arow * D + koff);
            float4 h1 = *(const float4*)(H + (long long)arow * D + koff + 4);
            float4 s0 = *(const float4*)(scale + koff);
            float4 s1 = *(const float4*)(scale + koff + 4);
            float4 t0 = *(const float4*)(shift + koff);
            float4 t1 = *(const float4*)(shift + koff + 4);
            a[kt][0] = f2bf(fmaxf(h0.x * s0.x + t0.x, 0.f));
            a[kt][1] = f2bf(fmaxf(h0.y * s0.y + t0.y, 0.f));
            a[kt][2] = f2bf(fmaxf(h0.z * s0.z + t0.z, 0.f));
            a[kt][3] = f2bf(fmaxf(h0.w * s0.w + t0.w, 0.f));
            a[kt][4] = f2bf(fmaxf(h1.x * s1.x + t1.x, 0.f));
            a[kt][5] = f2bf(fmaxf(h1.y * s1.y + t1.y, 0.f));
            a[kt][6] = f2bf(fmaxf(h1.z * s1.z + t1.z, 0.f));
            a[kt][7] = f2bf(fmaxf(h1.w * s1.w + t1.w, 0.f));
        } else {
            a[kt] = (short8)0;
        }
    }

    floatx4 acc[8];
    #pragma unroll
    for (int nt = 0; nt < 8; nt++) acc[nt] = (floatx4){0.f, 0.f, 0.f, 0.f};

    #pragma unroll
    for (int nt = 0; nt < 8; nt++) {
        #pragma unroll
        for (int kt = 0; kt < 4; kt++) {
            short8 bf = *(const short8*)(Wp + (size_t)((kt * 8 + nt) * 64 + lane) * 8);
            acc[nt] = __builtin_amdgcn_mfma_f32_16x16x32_bf16(a[kt], bf, acc[nt], 0, 0, 0);
        }
    }

    #pragma unroll
    for (int nt = 0; nt < 8; nt++) {
        int col = nt * 16 + m;
        float bcol = b[col];
        #pragma unroll
        for (int r = 0; r < 4; r++) {
            int grow = r0 + g * 4 + r;
            if (grow < N_NODES) {
                float y = acc[nt][r] + bcol;
                if (reluOut) y = fmaxf(y, 0.f);
                Y[(long long)grow * D + col] = y;
            }
        }
    }
}

// ---------------------------------------------------------------------------
extern "C" void kernel_launch(void* const* d_in, const int* in_sizes, int n_in,
                              void* d_out, int out_size, void* d_ws, size_t ws_size,
                              hipStream_t stream) {
    const float* x      = (const float*)d_in[0];
    const void*  ei     = d_in[1];
    const float* W1     = (const float*)d_in[2];
    const float* b1     = (const float*)d_in[3];
    const float* gamma  = (const float*)d_in[4];
    const float* beta   = (const float*)d_in[5];
    const float* W2     = (const float*)d_in[6];
    const float* b2     = (const float*)d_in[7];
    const float* epsArr = (const float*)d_in[8];
    float* out = (float*)d_out;

    char* ws = (char*)d_ws;
    const size_t fbuf = (size_t)N_NODES * D * sizeof(float);
    const size_t hbuf = (size_t)N_NODES * D * sizeof(short);
    float* Bh     = (float*)ws;                      // GEMM1 output (pre-BN, fp32)
    float* Bx     = (float*)(ws + fbuf);             // layer output / next x (fp32)
    unsigned* B16 = (unsigned*)(ws + 2 * fbuf);      // pre-MLP features, bf16 packed
    char* p       = ws + 2 * fbuf + hbuf;
    short* Wp     = (short*)p;           p += 6 * (size_t)D * D * sizeof(short);
    int* rowptr   = (int*)p;             p += (N_NODES + 1) * sizeof(int);
    int* deg      = (int*)p;             p += N_NODES * sizeof(int);
    int* cursor   = (int*)p;             p += N_NODES * sizeof(int);
    int* bsum     = (int*)p;             p += 256 * sizeof(int);
    int* csr      = (int*)p;             p += N_EDGES * sizeof(int);
    float* gsum   = (float*)p;           p += D * sizeof(float);
    float* gsq    = (float*)p;           p += D * sizeof(float);
    float* scale  = (float*)p;           p += D * sizeof(float);
    float* shift  = (float*)p;           p += D * sizeof(float);
    int* flag     = (int*)p;

    detect_i64_kernel<<<1, 256, 0, stream>>>((const int*)ei, flag);

    // Permute all 6 weight matrices into MFMA B-fragment bf16 layout.
    wperm_kernel<<<6 * 2048 / 256, 256, 0, stream>>>(W1, W2, Wp);

    // Build CSR once; reused by all 3 layers.
    hipMemsetAsync(deg, 0, N_NODES * sizeof(int), stream);
    degree_kernel<<<(N_EDGES + 255) / 256, 256, 0, stream>>>(ei, flag, deg);
    blocksum_kernel<<<SCAN_BLOCKS, 256, 0, stream>>>(deg, bsum);
    scan_bsum_kernel<<<1, 256, 0, stream>>>(bsum);
    rowptr_kernel<<<SCAN_BLOCKS, 256, 0, stream>>>(deg, bsum, rowptr, cursor);
    fill_kernel<<<(N_EDGES + 255) / 256, 256, 0, stream>>>(ei, flag, cursor, csr);

    const int gemmGrid = (N_NODES + 63) / 64;
    for (int l = 0; l < L_LAYERS; l++) {
        const float* xin = (l == 0) ? x : Bx;
        float* yout = (l == L_LAYERS - 1) ? out : Bx;

        hipMemsetAsync(gsum, 0, 2 * D * sizeof(float), stream);

        gather_prep_kernel<<<(N_NODES + 3) / 4, 256, 0, stream>>>(
            xin, rowptr, csr, epsArr, l, B16);
        gemm1_mfma_kernel<<<gemmGrid, 256, 0, stream>>>(
            (const short*)B16, Wp + (size_t)l * D * D, b1 + (size_t)l * D,
            Bh, gsum, gsq);
        bn_finalize_kernel<<<1, D, 0, stream>>>(gsum, gsq, gamma + (size_t)l * D,
                                                beta + (size_t)l * D, scale, shift);
        gemm2_mfma_kernel<<<gemmGrid, 256, 0, stream>>>(
            Bh, scale, shift, Wp + (size_t)(3 + l) * D * D, b2 + (size_t)l * D,
            yout, (l != L_LAYERS - 1) ? 1 : 0);
    }
}

// Round 5
// 483.252 us; speedup vs baseline: 9.1854x; 1.2601x over previous
//
#include <hip/hip_runtime.h>
#include <hip/hip_bf16.h>

#define N_NODES 50000
#define N_EDGES 800000
#define D 128
#define L_LAYERS 3
#define BN_EPS 1e-5f
#define SCAN_BLOCKS 196   // 196*256 = 50176 >= 50000

typedef __attribute__((ext_vector_type(8))) short short8;
typedef __attribute__((ext_vector_type(4))) float floatx4;
typedef __attribute__((ext_vector_type(4))) unsigned short ushort4v;

__device__ __forceinline__ unsigned short f2bf(float f) {
    unsigned u = __builtin_bit_cast(unsigned, f);
    u += 0x7FFFu + ((u >> 16) & 1u);   // round-to-nearest-even
    return (unsigned short)(u >> 16);
}
__device__ __forceinline__ float bf2f(unsigned short h) {
    unsigned u = ((unsigned)h) << 16;
    return __builtin_bit_cast(float, u);
}
__device__ __forceinline__ float bf2f_lo(unsigned p) {
    return __builtin_bit_cast(float, p << 16);
}
__device__ __forceinline__ float bf2f_hi(unsigned p) {
    return __builtin_bit_cast(float, p & 0xFFFF0000u);
}

// ---------------------------------------------------------------------------
// Detect whether edge_index arrived as int64 (odd int32 words all zero) or int32.
__global__ void detect_i64_kernel(const int* __restrict__ ei32, int* __restrict__ flag) {
    __shared__ int nz;
    if (threadIdx.x == 0) nz = 0;
    __syncthreads();
    int v = ei32[2 * threadIdx.x + 1];
    if (v != 0) atomicAdd(&nz, 1);
    __syncthreads();
    if (threadIdx.x == 0) *flag = (nz == 0) ? 1 : 0;
}

__device__ __forceinline__ int edge_at(const void* ei, const int* flag64, long long i) {
    if (*flag64) return (int)((const long long*)ei)[i];
    return ((const int*)ei)[i];
}

// ---------------------------------------------------------------------------
// fp32 -> bf16 conversion of the initial node features (one-time).
__global__ __launch_bounds__(256) void cvt_kernel(const float* __restrict__ x,
        unsigned short* __restrict__ xb) {
    long long i = (long long)(blockIdx.x * 256 + threadIdx.x) * 4;
    float4 v = *(const float4*)(x + i);
    ushort4v o;
    o.x = f2bf(v.x); o.y = f2bf(v.y); o.z = f2bf(v.z); o.w = f2bf(v.w);
    *(ushort4v*)(xb + i) = o;
}

// ---------------------------------------------------------------------------
// CSR build step 1: in-degree histogram over dst.
__global__ __launch_bounds__(256) void degree_kernel(const void* __restrict__ ei,
        const int* __restrict__ flag64, int* __restrict__ deg) {
    int e = blockIdx.x * 256 + threadIdx.x;
    if (e >= N_EDGES) return;
    int dst = edge_at(ei, flag64, (long long)N_EDGES + e);
    atomicAdd(&deg[dst], 1);
}

// CSR build step 2a: per-block (256-elem) sums of deg.
__global__ __launch_bounds__(256) void blocksum_kernel(const int* __restrict__ deg,
        int* __restrict__ bsum) {
    int i = blockIdx.x * 256 + threadIdx.x;
    int v = (i < N_NODES) ? deg[i] : 0;
    #pragma unroll
    for (int m = 32; m >= 1; m >>= 1) v += __shfl_xor(v, m);
    __shared__ int ws_[4];
    if ((threadIdx.x & 63) == 0) ws_[threadIdx.x >> 6] = v;
    __syncthreads();
    if (threadIdx.x == 0) bsum[blockIdx.x] = ws_[0] + ws_[1] + ws_[2] + ws_[3];
}

// CSR build step 2b: exclusive scan of the 196 block sums (1 block).
__global__ __launch_bounds__(256) void scan_bsum_kernel(int* __restrict__ bsum) {
    __shared__ int s[256];
    int t = threadIdx.x;
    int v = (t < SCAN_BLOCKS) ? bsum[t] : 0;
    s[t] = v;
    __syncthreads();
    for (int off = 1; off < 256; off <<= 1) {
        int u = (t >= off) ? s[t - off] : 0;
        __syncthreads();
        s[t] += u;
        __syncthreads();
    }
    if (t < SCAN_BLOCKS) bsum[t] = s[t] - v;   // exclusive
}

// CSR build step 2c: per-block local scan + block offset -> rowptr, cursor.
__global__ __launch_bounds__(256) void rowptr_kernel(const int* __restrict__ deg,
        const int* __restrict__ bsum, int* __restrict__ rowptr, int* __restrict__ cursor) {
    __shared__ int s[256];
    int i = blockIdx.x * 256 + threadIdx.x;
    int v = (i < N_NODES) ? deg[i] : 0;
    s[threadIdx.x] = v;
    __syncthreads();
    for (int off = 1; off < 256; off <<= 1) {
        int u = (threadIdx.x >= off) ? s[threadIdx.x - off] : 0;
        __syncthreads();
        s[threadIdx.x] += u;
        __syncthreads();
    }
    int excl = s[threadIdx.x] - v + bsum[blockIdx.x];
    if (i < N_NODES) { rowptr[i] = excl; cursor[i] = excl; }
    if (i == N_NODES) rowptr[N_NODES] = N_EDGES;
}

// CSR build step 3: fill neighbor (src) lists via per-node cursors.
__global__ __launch_bounds__(256) void fill_kernel(const void* __restrict__ ei,
        const int* __restrict__ flag64, int* __restrict__ cursor, int* __restrict__ csr) {
    int e = blockIdx.x * 256 + threadIdx.x;
    if (e >= N_EDGES) return;
    int src = edge_at(ei, flag64, e);
    int dst = edge_at(ei, flag64, (long long)N_EDGES + e);
    int pos = atomicAdd(&cursor[dst], 1);
    csr[pos] = src;
}

// ---------------------------------------------------------------------------
// Pre-permute W (fp32 [k][n]) into bf16 MFMA B-fragment order.
__global__ __launch_bounds__(256) void wperm_kernel(const float* __restrict__ W1,
        const float* __restrict__ W2, short* __restrict__ Wp) {
    int tid = blockIdx.x * 256 + threadIdx.x;   // 6*2048 total
    int mat = tid >> 11;
    int t2 = tid & 2047;
    int kt = t2 >> 9;
    int nt = (t2 >> 6) & 7;
    int lane = t2 & 63;
    const float* W = (mat < 3) ? (W1 + (size_t)mat * D * D)
                               : (W2 + (size_t)(mat - 3) * D * D);
    int kbase = kt * 32 + (lane >> 4) * 8;
    int n = nt * 16 + (lane & 15);
    short8 frag;
    #pragma unroll
    for (int j = 0; j < 8; j++) frag[j] = (short)f2bf(W[(kbase + j) * D + n]);
    *(short8*)(Wp + (size_t)mat * D * D + (size_t)t2 * 8) = frag;
}

// ---------------------------------------------------------------------------
// Per node: agg = sum_{j in N(i)} xb[j];  out = l2norm(agg) + (1+eps)*l2norm(xb_i)
// One wave per row; bf16 input; neighbor indices preloaded coalesced + shfl
// broadcast; x-row loads unrolled x4 into independent accumulators.
__global__ __launch_bounds__(256) void gather_prep_kernel(
        const unsigned short* __restrict__ xb,
        const int* __restrict__ rowptr, const int* __restrict__ csr,
        const float* __restrict__ epsArr, int layer, unsigned* __restrict__ out16) {
    int row = blockIdx.x * 4 + (threadIdx.x >> 6);
    if (row >= N_NODES) return;
    int lane = threadIdx.x & 63;
    int beg = rowptr[row], end = rowptr[row + 1];

    float a0 = 0.f, a1 = 0.f, b0 = 0.f, b1 = 0.f;
    float c0 = 0.f, c1 = 0.f, d0 = 0.f, d1 = 0.f;

    for (int base = beg; base < end; base += 64) {
        int n = end - base;
        if (n > 64) n = 64;
        int idx = (lane < n) ? csr[base + lane] : 0;
        int j = 0;
        for (; j + 3 < n; j += 4) {
            int s0 = __shfl(idx, j);
            int s1 = __shfl(idx, j + 1);
            int s2 = __shfl(idx, j + 2);
            int s3 = __shfl(idx, j + 3);
            unsigned p0 = *(const unsigned*)(xb + (long long)s0 * D + lane * 2);
            unsigned p1 = *(const unsigned*)(xb + (long long)s1 * D + lane * 2);
            unsigned p2 = *(const unsigned*)(xb + (long long)s2 * D + lane * 2);
            unsigned p3 = *(const unsigned*)(xb + (long long)s3 * D + lane * 2);
            a0 += bf2f_lo(p0); a1 += bf2f_hi(p0);
            b0 += bf2f_lo(p1); b1 += bf2f_hi(p1);
            c0 += bf2f_lo(p2); c1 += bf2f_hi(p2);
            d0 += bf2f_lo(p3); d1 += bf2f_hi(p3);
        }
        for (; j < n; j++) {
            int s0 = __shfl(idx, j);
            unsigned p0 = *(const unsigned*)(xb + (long long)s0 * D + lane * 2);
            a0 += bf2f_lo(p0); a1 += bf2f_hi(p0);
        }
    }
    float ax = a0 + b0 + c0 + d0;
    float ay = a1 + b1 + c1 + d1;

    unsigned pself = *(const unsigned*)(xb + (long long)row * D + lane * 2);
    float xv0 = bf2f_lo(pself), xv1 = bf2f_hi(pself);

    float sa = ax * ax + ay * ay;
    float sx = xv0 * xv0 + xv1 * xv1;
    #pragma unroll
    for (int m = 32; m >= 1; m >>= 1) {
        sa += __shfl_xor(sa, m);
        sx += __shfl_xor(sx, m);
    }
    float ra = 1.0f / fmaxf(sqrtf(sa), 1e-12f);
    float rx = (1.0f + epsArr[layer]) / fmaxf(sqrtf(sx), 1e-12f);
    float ox = ax * ra + xv0 * rx;
    float oy = ay * ra + xv1 * rx;
    unsigned pack = (unsigned)f2bf(ox) | ((unsigned)f2bf(oy) << 16);
    out16[(long long)row * 64 + lane] = pack;
}

// ---------------------------------------------------------------------------
// GEMM1 (MFMA bf16): H(bf16) = A@W1 + b1, plus fp32 per-column BN stats.
__global__ __launch_bounds__(256) void gemm1_mfma_kernel(const short* __restrict__ Ab,
        const short* __restrict__ Wp, const float* __restrict__ b,
        unsigned short* __restrict__ Hout, float* __restrict__ gsum, float* __restrict__ gsq) {
    __shared__ float lsum[D];
    __shared__ float lsq[D];
    if (threadIdx.x < D) { lsum[threadIdx.x] = 0.f; lsq[threadIdx.x] = 0.f; }
    __syncthreads();

    int wave = threadIdx.x >> 6, lane = threadIdx.x & 63;
    int r0 = blockIdx.x * 64 + wave * 16;
    int m = lane & 15, g = lane >> 4;
    int arow = r0 + m;
    bool valid = arow < N_NODES;

    short8 a[4];
    #pragma unroll
    for (int kt = 0; kt < 4; kt++) {
        if (valid) {
            a[kt] = *(const short8*)(Ab + (long long)arow * D + kt * 32 + g * 8);
        } else {
            a[kt] = (short8)0;
        }
    }

    floatx4 acc[8];
    #pragma unroll
    for (int nt = 0; nt < 8; nt++) acc[nt] = (floatx4){0.f, 0.f, 0.f, 0.f};

    #pragma unroll
    for (int nt = 0; nt < 8; nt++) {
        #pragma unroll
        for (int kt = 0; kt < 4; kt++) {
            short8 bf = *(const short8*)(Wp + (size_t)((kt * 8 + nt) * 64 + lane) * 8);
            acc[nt] = __builtin_amdgcn_mfma_f32_16x16x32_bf16(a[kt], bf, acc[nt], 0, 0, 0);
        }
    }

    #pragma unroll
    for (int nt = 0; nt < 8; nt++) {
        int col = nt * 16 + m;
        float bcol = b[col];
        float s = 0.f, q = 0.f;
        #pragma unroll
        for (int r = 0; r < 4; r++) {
            int grow = r0 + g * 4 + r;
            if (grow < N_NODES) {
                float h = acc[nt][r] + bcol;
                Hout[(long long)grow * D + col] = f2bf(h);
                s += h; q += h * h;
            }
        }
        s += __shfl_xor(s, 16); s += __shfl_xor(s, 32);
        q += __shfl_xor(q, 16); q += __shfl_xor(q, 32);
        if (lane < 16) {
            atomicAdd(&lsum[col], s);
            atomicAdd(&lsq[col], q);
        }
    }
    __syncthreads();
    if (threadIdx.x < D) {
        atomicAdd(&gsum[threadIdx.x], lsum[threadIdx.x]);
        atomicAdd(&gsq[threadIdx.x], lsq[threadIdx.x]);
    }
}

// ---------------------------------------------------------------------------
__global__ void bn_finalize_kernel(const float* __restrict__ gsum, const float* __restrict__ gsq,
        const float* __restrict__ gamma, const float* __restrict__ beta,
        float* __restrict__ scale, float* __restrict__ shift) {
    int c = threadIdx.x;
    const float invN = 1.0f / (float)N_NODES;
    float mu = gsum[c] * invN;
    float var = fmaxf(gsq[c] * invN - mu * mu, 0.f);
    float is = rsqrtf(var + BN_EPS);
    float sc = gamma[c] * is;
    scale[c] = sc;
    shift[c] = beta[c] - mu * sc;
}

// ---------------------------------------------------------------------------
// GEMM2 (MFMA bf16): Y = relu(scale*H+shift) @ W2 + b2.
// Non-final layers: relu(Y) written as bf16 into Xb (next gather input).
// Final layer: Y written fp32 into out.
__global__ __launch_bounds__(256) void gemm2_mfma_kernel(const unsigned short* __restrict__ H,
        const float* __restrict__ scale, const float* __restrict__ shift,
        const short* __restrict__ Wp, const float* __restrict__ b,
        float* __restrict__ Yf32, unsigned short* __restrict__ Yb16, int finalLayer) {
    int wave = threadIdx.x >> 6, lane = threadIdx.x & 63;
    int r0 = blockIdx.x * 64 + wave * 16;
    int m = lane & 15, g = lane >> 4;
    int arow = r0 + m;
    bool valid = arow < N_NODES;

    short8 a[4];
    #pragma unroll
    for (int kt = 0; kt < 4; kt++) {
        int koff = kt * 32 + g * 8;
        if (valid) {
            short8 hv = *(const short8*)(H + (long long)arow * D + koff);
            #pragma unroll
            for (int j = 0; j < 8; j++) {
                float h = bf2f((unsigned short)hv[j]);
                float v = fmaxf(h * scale[koff + j] + shift[koff + j], 0.f);
                a[kt][j] = (short)f2bf(v);
            }
        } else {
            a[kt] = (short8)0;
        }
    }

    floatx4 acc[8];
    #pragma unroll
    for (int nt = 0; nt < 8; nt++) acc[nt] = (floatx4){0.f, 0.f, 0.f, 0.f};

    #pragma unroll
    for (int nt = 0; nt < 8; nt++) {
        #pragma unroll
        for (int kt = 0; kt < 4; kt++) {
            short8 bf = *(const short8*)(Wp + (size_t)((kt * 8 + nt) * 64 + lane) * 8);
            acc[nt] = __builtin_amdgcn_mfma_f32_16x16x32_bf16(a[kt], bf, acc[nt], 0, 0, 0);
        }
    }

    #pragma unroll
    for (int nt = 0; nt < 8; nt++) {
        int col = nt * 16 + m;
        float bcol = b[col];
        #pragma unroll
        for (int r = 0; r < 4; r++) {
            int grow = r0 + g * 4 + r;
            if (grow < N_NODES) {
                float y = acc[nt][r] + bcol;
                if (finalLayer) {
                    Yf32[(long long)grow * D + col] = y;
                } else {
                    Yb16[(long long)grow * D + col] = f2bf(fmaxf(y, 0.f));
                }
            }
        }
    }
}

// ---------------------------------------------------------------------------
extern "C" void kernel_launch(void* const* d_in, const int* in_sizes, int n_in,
                              void* d_out, int out_size, void* d_ws, size_t ws_size,
                              hipStream_t stream) {
    const float* x      = (const float*)d_in[0];
    const void*  ei     = d_in[1];
    const float* W1     = (const float*)d_in[2];
    const float* b1     = (const float*)d_in[3];
    const float* gamma  = (const float*)d_in[4];
    const float* beta   = (const float*)d_in[5];
    const float* W2     = (const float*)d_in[6];
    const float* b2     = (const float*)d_in[7];
    const float* epsArr = (const float*)d_in[8];
    float* out = (float*)d_out;

    char* ws = (char*)d_ws;
    const size_t hbuf = (size_t)N_NODES * D * sizeof(short);   // 12.8 MB
    unsigned short* Xb  = (unsigned short*)ws;                 // gather input (bf16)
    unsigned* B16       = (unsigned*)(ws + hbuf);              // gather out / gemm1 A
    unsigned short* H16 = (unsigned short*)(ws + 2 * hbuf);    // gemm1 out (bf16)
    char* p             = ws + 3 * hbuf;
    short* Wp     = (short*)p;           p += 6 * (size_t)D * D * sizeof(short);
    int* rowptr   = (int*)p;             p += (N_NODES + 1) * sizeof(int);
    int* deg      = (int*)p;             p += N_NODES * sizeof(int);
    int* cursor   = (int*)p;             p += N_NODES * sizeof(int);
    int* bsum     = (int*)p;             p += 256 * sizeof(int);
    int* csr      = (int*)p;             p += N_EDGES * sizeof(int);
    float* gsum   = (float*)p;           p += D * sizeof(float);
    float* gsq    = (float*)p;           p += D * sizeof(float);
    float* scale  = (float*)p;           p += D * sizeof(float);
    float* shift  = (float*)p;           p += D * sizeof(float);
    int* flag     = (int*)p;

    detect_i64_kernel<<<1, 256, 0, stream>>>((const int*)ei, flag);

    // One-time: weights to MFMA bf16 fragments; x to bf16.
    wperm_kernel<<<6 * 2048 / 256, 256, 0, stream>>>(W1, W2, Wp);
    cvt_kernel<<<(N_NODES * D / 4) / 256, 256, 0, stream>>>(x, Xb);

    // Build CSR once; reused by all 3 layers.
    hipMemsetAsync(deg, 0, N_NODES * sizeof(int), stream);
    degree_kernel<<<(N_EDGES + 255) / 256, 256, 0, stream>>>(ei, flag, deg);
    blocksum_kernel<<<SCAN_BLOCKS, 256, 0, stream>>>(deg, bsum);
    scan_bsum_kernel<<<1, 256, 0, stream>>>(bsum);
    rowptr_kernel<<<SCAN_BLOCKS, 256, 0, stream>>>(deg, bsum, rowptr, cursor);
    fill_kernel<<<(N_EDGES + 255) / 256, 256, 0, stream>>>(ei, flag, cursor, csr);

    const int gemmGrid = (N_NODES + 63) / 64;
    for (int l = 0; l < L_LAYERS; l++) {
        int fin = (l == L_LAYERS - 1) ? 1 : 0;

        hipMemsetAsync(gsum, 0, 2 * D * sizeof(float), stream);

        gather_prep_kernel<<<(N_NODES + 3) / 4, 256, 0, stream>>>(
            Xb, rowptr, csr, epsArr, l, B16);
        gemm1_mfma_kernel<<<gemmGrid, 256, 0, stream>>>(
            (const short*)B16, Wp + (size_t)l * D * D, b1 + (size_t)l * D,
            H16, gsum, gsq);
        bn_finalize_kernel<<<1, D, 0, stream>>>(gsum, gsq, gamma + (size_t)l * D,
                                                beta + (size_t)l * D, scale, shift);
        gemm2_mfma_kernel<<<gemmGrid, 256, 0, stream>>>(
            H16, scale, shift, Wp + (size_t)(3 + l) * D * D, b2 + (size_t)l * D,
            out, Xb, fin);
    }
}

// Round 6
// 406.198 us; speedup vs baseline: 10.9278x; 1.1897x over previous
//
#include <hip/hip_runtime.h>
#include <hip/hip_bf16.h>

#define N_NODES 50000
#define N_EDGES 800000
#define D 128
#define L_LAYERS 3
#define BN_EPS 1e-5f
#define NBUK 196          // buckets of 256 dst values: 196*256 = 50176 >= 50000
#define BIN_CHUNK 4096    // edges per block in count/bin: 196*4096 >= 800000
#define NBIN_BLOCKS 196

typedef __attribute__((ext_vector_type(8))) short short8;
typedef __attribute__((ext_vector_type(4))) float floatx4;
typedef __attribute__((ext_vector_type(4))) unsigned short ushort4v;

__device__ __forceinline__ unsigned short f2bf(float f) {
    unsigned u = __builtin_bit_cast(unsigned, f);
    u += 0x7FFFu + ((u >> 16) & 1u);   // round-to-nearest-even
    return (unsigned short)(u >> 16);
}
__device__ __forceinline__ float bf2f(unsigned short h) {
    unsigned u = ((unsigned)h) << 16;
    return __builtin_bit_cast(float, u);
}
__device__ __forceinline__ float bf2f_lo(unsigned p) {
    return __builtin_bit_cast(float, p << 16);
}
__device__ __forceinline__ float bf2f_hi(unsigned p) {
    return __builtin_bit_cast(float, p & 0xFFFF0000u);
}

// ---------------------------------------------------------------------------
__global__ void detect_i64_kernel(const int* __restrict__ ei32, int* __restrict__ flag) {
    __shared__ int nz;
    if (threadIdx.x == 0) nz = 0;
    __syncthreads();
    int v = ei32[2 * threadIdx.x + 1];
    if (v != 0) atomicAdd(&nz, 1);
    __syncthreads();
    if (threadIdx.x == 0) *flag = (nz == 0) ? 1 : 0;
}

__device__ __forceinline__ int edge_at(const void* ei, const int* flag64, long long i) {
    if (*flag64) return (int)((const long long*)ei)[i];
    return ((const int*)ei)[i];
}

// ---------------------------------------------------------------------------
// fp32 -> bf16 conversion of the initial node features (one-time).
__global__ __launch_bounds__(256) void cvt_kernel(const float* __restrict__ x,
        unsigned short* __restrict__ xb) {
    long long i = (long long)(blockIdx.x * 256 + threadIdx.x) * 4;
    float4 v = *(const float4*)(x + i);
    ushort4v o;
    o.x = f2bf(v.x); o.y = f2bf(v.y); o.z = f2bf(v.z); o.w = f2bf(v.w);
    *(ushort4v*)(xb + i) = o;
}

// ---------------------------------------------------------------------------
// CSR stage 1: bucket (dst>>8) histogram. LDS-staged, 196 global atomics/block.
__global__ __launch_bounds__(256) void count_kernel(const void* __restrict__ ei,
        const int* __restrict__ flag64, int* __restrict__ bucketCount) {
    __shared__ int lhist[NBUK];
    int t = threadIdx.x;
    for (int i = t; i < NBUK; i += 256) lhist[i] = 0;
    __syncthreads();
    int e0 = blockIdx.x * BIN_CHUNK;
    #pragma unroll
    for (int i = 0; i < BIN_CHUNK / 256; i++) {
        int e = e0 + t + i * 256;
        if (e < N_EDGES) {
            int d = edge_at(ei, flag64, (long long)N_EDGES + e);
            atomicAdd(&lhist[d >> 8], 1);
        }
    }
    __syncthreads();
    for (int i = t; i < NBUK; i += 256)
        if (lhist[i]) atomicAdd(&bucketCount[i], lhist[i]);
}

// CSR stage 2: scan bucket counts -> bases + cursors (1 block).
__global__ __launch_bounds__(256) void bucket_scan_kernel(const int* __restrict__ bucketCount,
        int* __restrict__ bucketBase, int* __restrict__ bucketCursor) {
    __shared__ int s[256];
    int t = threadIdx.x;
    int v = (t < NBUK) ? bucketCount[t] : 0;
    s[t] = v;
    __syncthreads();
    for (int off = 1; off < 256; off <<= 1) {
        int u = (t >= off) ? s[t - off] : 0;
        __syncthreads();
        s[t] += u;
        __syncthreads();
    }
    int excl = s[t] - v;
    if (t < NBUK) { bucketBase[t] = excl; bucketCursor[t] = excl; }
    if (t == 0) bucketBase[NBUK] = N_EDGES;
}

// CSR stage 3: partition edges into bucket-ordered packed words.
// word = (src << 8) | (dst & 255); src < 65536 so it fits in 24 bits.
__global__ __launch_bounds__(256) void bin_kernel(const void* __restrict__ ei,
        const int* __restrict__ flag64, int* __restrict__ bucketCursor,
        unsigned* __restrict__ binned) {
    __shared__ int lhist[NBUK];
    __shared__ int gbase[NBUK];
    int t = threadIdx.x;
    for (int i = t; i < NBUK; i += 256) lhist[i] = 0;
    __syncthreads();
    int e0 = blockIdx.x * BIN_CHUNK;
    unsigned w[BIN_CHUNK / 256];
    short bkt[BIN_CHUNK / 256];
    short lidx[BIN_CHUNK / 256];
    #pragma unroll
    for (int i = 0; i < BIN_CHUNK / 256; i++) {
        int e = e0 + t + i * 256;
        if (e < N_EDGES) {
            int s = edge_at(ei, flag64, e);
            int d = edge_at(ei, flag64, (long long)N_EDGES + e);
            int b = d >> 8;
            w[i] = ((unsigned)s << 8) | (unsigned)(d & 255);
            bkt[i] = (short)b;
            lidx[i] = (short)atomicAdd(&lhist[b], 1);
        } else {
            bkt[i] = -1;
        }
    }
    __syncthreads();
    for (int i = t; i < NBUK; i += 256)
        gbase[i] = lhist[i] ? atomicAdd(&bucketCursor[i], lhist[i]) : 0;
    __syncthreads();
    #pragma unroll
    for (int i = 0; i < BIN_CHUNK / 256; i++) {
        if (bkt[i] >= 0)
            binned[gbase[bkt[i]] + (int)lidx[i]] = w[i];
    }
}

// CSR stage 4: one block per bucket; all scatter via LDS; coalesced rowptr.
__global__ __launch_bounds__(256) void csr_build_kernel(const unsigned* __restrict__ binned,
        const int* __restrict__ bucketBase, int* __restrict__ rowptr, int* __restrict__ csr) {
    __shared__ int lhist[256];
    __shared__ int ls[256];
    __shared__ int lcur[256];
    int b = blockIdx.x, t = threadIdx.x;
    int base = bucketBase[b], endp = bucketBase[b + 1];
    int n = endp - base;
    lhist[t] = 0;
    __syncthreads();
    for (int i = t; i < n; i += 256)
        atomicAdd(&lhist[binned[base + i] & 255u], 1);
    __syncthreads();
    int v = lhist[t];
    ls[t] = v;
    __syncthreads();
    for (int off = 1; off < 256; off <<= 1) {
        int u = (t >= off) ? ls[t - off] : 0;
        __syncthreads();
        ls[t] += u;
        __syncthreads();
    }
    int excl = ls[t] - v;
    int dst = b * 256 + t;
    if (dst <= N_NODES) rowptr[dst] = base + excl;
    lcur[t] = excl;
    __syncthreads();
    for (int i = t; i < n; i += 256) {
        unsigned wv = binned[base + i];
        int pos = atomicAdd(&lcur[wv & 255u], 1);
        csr[base + pos] = (int)(wv >> 8);
    }
}

// ---------------------------------------------------------------------------
// Pre-permute W (fp32 [k][n]) into bf16 MFMA B-fragment order.
__global__ __launch_bounds__(256) void wperm_kernel(const float* __restrict__ W1,
        const float* __restrict__ W2, short* __restrict__ Wp) {
    int tid = blockIdx.x * 256 + threadIdx.x;   // 6*2048 total
    int mat = tid >> 11;
    int t2 = tid & 2047;
    int kt = t2 >> 9;
    int nt = (t2 >> 6) & 7;
    int lane = t2 & 63;
    const float* W = (mat < 3) ? (W1 + (size_t)mat * D * D)
                               : (W2 + (size_t)(mat - 3) * D * D);
    int kbase = kt * 32 + (lane >> 4) * 8;
    int n = nt * 16 + (lane & 15);
    short8 frag;
    #pragma unroll
    for (int j = 0; j < 8; j++) frag[j] = (short)f2bf(W[(kbase + j) * D + n]);
    *(short8*)(Wp + (size_t)mat * D * D + (size_t)t2 * 8) = frag;
}

// ---------------------------------------------------------------------------
// Per node: agg = sum_{j in N(i)} xb[j];  out = l2norm(agg) + (1+eps)*l2norm(xb_i)
__global__ __launch_bounds__(256) void gather_prep_kernel(
        const unsigned short* __restrict__ xb,
        const int* __restrict__ rowptr, const int* __restrict__ csr,
        const float* __restrict__ epsArr, int layer, unsigned* __restrict__ out16) {
    int row = blockIdx.x * 4 + (threadIdx.x >> 6);
    if (row >= N_NODES) return;
    int lane = threadIdx.x & 63;
    int beg = rowptr[row], end = rowptr[row + 1];

    float a0 = 0.f, a1 = 0.f, b0 = 0.f, b1 = 0.f;
    float c0 = 0.f, c1 = 0.f, d0 = 0.f, d1 = 0.f;

    for (int base = beg; base < end; base += 64) {
        int n = end - base;
        if (n > 64) n = 64;
        int idx = (lane < n) ? csr[base + lane] : 0;
        int j = 0;
        for (; j + 3 < n; j += 4) {
            int s0 = __shfl(idx, j);
            int s1 = __shfl(idx, j + 1);
            int s2 = __shfl(idx, j + 2);
            int s3 = __shfl(idx, j + 3);
            unsigned p0 = *(const unsigned*)(xb + (long long)s0 * D + lane * 2);
            unsigned p1 = *(const unsigned*)(xb + (long long)s1 * D + lane * 2);
            unsigned p2 = *(const unsigned*)(xb + (long long)s2 * D + lane * 2);
            unsigned p3 = *(const unsigned*)(xb + (long long)s3 * D + lane * 2);
            a0 += bf2f_lo(p0); a1 += bf2f_hi(p0);
            b0 += bf2f_lo(p1); b1 += bf2f_hi(p1);
            c0 += bf2f_lo(p2); c1 += bf2f_hi(p2);
            d0 += bf2f_lo(p3); d1 += bf2f_hi(p3);
        }
        for (; j < n; j++) {
            int s0 = __shfl(idx, j);
            unsigned p0 = *(const unsigned*)(xb + (long long)s0 * D + lane * 2);
            a0 += bf2f_lo(p0); a1 += bf2f_hi(p0);
        }
    }
    float ax = a0 + b0 + c0 + d0;
    float ay = a1 + b1 + c1 + d1;

    unsigned pself = *(const unsigned*)(xb + (long long)row * D + lane * 2);
    float xv0 = bf2f_lo(pself), xv1 = bf2f_hi(pself);

    float sa = ax * ax + ay * ay;
    float sx = xv0 * xv0 + xv1 * xv1;
    #pragma unroll
    for (int m = 32; m >= 1; m >>= 1) {
        sa += __shfl_xor(sa, m);
        sx += __shfl_xor(sx, m);
    }
    float ra = 1.0f / fmaxf(sqrtf(sa), 1e-12f);
    float rx = (1.0f + epsArr[layer]) / fmaxf(sqrtf(sx), 1e-12f);
    float ox = ax * ra + xv0 * rx;
    float oy = ay * ra + xv1 * rx;
    unsigned pack = (unsigned)f2bf(ox) | ((unsigned)f2bf(oy) << 16);
    out16[(long long)row * 64 + lane] = pack;
}

// ---------------------------------------------------------------------------
// GEMM1 (MFMA bf16): H(bf16) = A@W1 + b1, plus fp32 per-column BN stats.
__global__ __launch_bounds__(256) void gemm1_mfma_kernel(const short* __restrict__ Ab,
        const short* __restrict__ Wp, const float* __restrict__ b,
        unsigned short* __restrict__ Hout, float* __restrict__ gsum, float* __restrict__ gsq) {
    __shared__ float lsum[D];
    __shared__ float lsq[D];
    if (threadIdx.x < D) { lsum[threadIdx.x] = 0.f; lsq[threadIdx.x] = 0.f; }
    __syncthreads();

    int wave = threadIdx.x >> 6, lane = threadIdx.x & 63;
    int r0 = blockIdx.x * 64 + wave * 16;
    int m = lane & 15, g = lane >> 4;
    int arow = r0 + m;
    bool valid = arow < N_NODES;

    short8 a[4];
    #pragma unroll
    for (int kt = 0; kt < 4; kt++) {
        if (valid) {
            a[kt] = *(const short8*)(Ab + (long long)arow * D + kt * 32 + g * 8);
        } else {
            a[kt] = (short8)0;
        }
    }

    floatx4 acc[8];
    #pragma unroll
    for (int nt = 0; nt < 8; nt++) acc[nt] = (floatx4){0.f, 0.f, 0.f, 0.f};

    #pragma unroll
    for (int nt = 0; nt < 8; nt++) {
        #pragma unroll
        for (int kt = 0; kt < 4; kt++) {
            short8 bf = *(const short8*)(Wp + (size_t)((kt * 8 + nt) * 64 + lane) * 8);
            acc[nt] = __builtin_amdgcn_mfma_f32_16x16x32_bf16(a[kt], bf, acc[nt], 0, 0, 0);
        }
    }

    #pragma unroll
    for (int nt = 0; nt < 8; nt++) {
        int col = nt * 16 + m;
        float bcol = b[col];
        float s = 0.f, q = 0.f;
        #pragma unroll
        for (int r = 0; r < 4; r++) {
            int grow = r0 + g * 4 + r;
            if (grow < N_NODES) {
                float h = acc[nt][r] + bcol;
                Hout[(long long)grow * D + col] = f2bf(h);
                s += h; q += h * h;
            }
        }
        s += __shfl_xor(s, 16); s += __shfl_xor(s, 32);
        q += __shfl_xor(q, 16); q += __shfl_xor(q, 32);
        if (lane < 16) {
            atomicAdd(&lsum[col], s);
            atomicAdd(&lsq[col], q);
        }
    }
    __syncthreads();
    if (threadIdx.x < D) {
        atomicAdd(&gsum[threadIdx.x], lsum[threadIdx.x]);
        atomicAdd(&gsq[threadIdx.x], lsq[threadIdx.x]);
    }
}

// ---------------------------------------------------------------------------
// GEMM2 (MFMA bf16): Y = relu(scale*H+shift) @ W2 + b2, BN finalize fused
// (each block recomputes scale/shift from the global stats).
__global__ __launch_bounds__(256) void gemm2_mfma_kernel(const unsigned short* __restrict__ H,
        const float* __restrict__ gsum, const float* __restrict__ gsq,
        const float* __restrict__ gamma, const float* __restrict__ beta,
        const short* __restrict__ Wp, const float* __restrict__ b,
        float* __restrict__ Yf32, unsigned short* __restrict__ Yb16, int finalLayer) {
    __shared__ float s_scale[D];
    __shared__ float s_shift[D];
    if (threadIdx.x < D) {
        int c = threadIdx.x;
        const float invN = 1.0f / (float)N_NODES;
        float mu = gsum[c] * invN;
        float var = fmaxf(gsq[c] * invN - mu * mu, 0.f);
        float is = rsqrtf(var + BN_EPS);
        float sc = gamma[c] * is;
        s_scale[c] = sc;
        s_shift[c] = beta[c] - mu * sc;
    }
    __syncthreads();

    int wave = threadIdx.x >> 6, lane = threadIdx.x & 63;
    int r0 = blockIdx.x * 64 + wave * 16;
    int m = lane & 15, g = lane >> 4;
    int arow = r0 + m;
    bool valid = arow < N_NODES;

    short8 a[4];
    #pragma unroll
    for (int kt = 0; kt < 4; kt++) {
        int koff = kt * 32 + g * 8;
        if (valid) {
            short8 hv = *(const short8*)(H + (long long)arow * D + koff);
            #pragma unroll
            for (int j = 0; j < 8; j++) {
                float h = bf2f((unsigned short)hv[j]);
                float v = fmaxf(h * s_scale[koff + j] + s_shift[koff + j], 0.f);
                a[kt][j] = (short)f2bf(v);
            }
        } else {
            a[kt] = (short8)0;
        }
    }

    floatx4 acc[8];
    #pragma unroll
    for (int nt = 0; nt < 8; nt++) acc[nt] = (floatx4){0.f, 0.f, 0.f, 0.f};

    #pragma unroll
    for (int nt = 0; nt < 8; nt++) {
        #pragma unroll
        for (int kt = 0; kt < 4; kt++) {
            short8 bf = *(const short8*)(Wp + (size_t)((kt * 8 + nt) * 64 + lane) * 8);
            acc[nt] = __builtin_amdgcn_mfma_f32_16x16x32_bf16(a[kt], bf, acc[nt], 0, 0, 0);
        }
    }

    #pragma unroll
    for (int nt = 0; nt < 8; nt++) {
        int col = nt * 16 + m;
        float bcol = b[col];
        #pragma unroll
        for (int r = 0; r < 4; r++) {
            int grow = r0 + g * 4 + r;
            if (grow < N_NODES) {
                float y = acc[nt][r] + bcol;
                if (finalLayer) {
                    Yf32[(long long)grow * D + col] = y;
                } else {
                    Yb16[(long long)grow * D + col] = f2bf(fmaxf(y, 0.f));
                }
            }
        }
    }
}

// ---------------------------------------------------------------------------
extern "C" void kernel_launch(void* const* d_in, const int* in_sizes, int n_in,
                              void* d_out, int out_size, void* d_ws, size_t ws_size,
                              hipStream_t stream) {
    const float* x      = (const float*)d_in[0];
    const void*  ei     = d_in[1];
    const float* W1     = (const float*)d_in[2];
    const float* b1     = (const float*)d_in[3];
    const float* gamma  = (const float*)d_in[4];
    const float* beta   = (const float*)d_in[5];
    const float* W2     = (const float*)d_in[6];
    const float* b2     = (const float*)d_in[7];
    const float* epsArr = (const float*)d_in[8];
    float* out = (float*)d_out;

    char* ws = (char*)d_ws;
    const size_t hbuf = (size_t)N_NODES * D * sizeof(short);   // 12.8 MB
    unsigned short* Xb  = (unsigned short*)ws;                 // gather input (bf16)
    unsigned* B16       = (unsigned*)(ws + hbuf);              // gather out / gemm1 A
    unsigned short* H16 = (unsigned short*)(ws + 2 * hbuf);    // gemm1 out (bf16)
    char* p             = ws + 3 * hbuf;
    short* Wp       = (short*)p;         p += 6 * (size_t)D * D * sizeof(short);
    int* rowptr     = (int*)p;           p += (N_NODES + 1) * sizeof(int);
    int* csr        = (int*)p;           p += N_EDGES * sizeof(int);
    unsigned* binned= (unsigned*)p;      p += N_EDGES * sizeof(unsigned);
    int* bucketBase = (int*)p;           p += (NBUK + 1) * sizeof(int);
    int* bucketCursor=(int*)p;           p += NBUK * sizeof(int);
    int* flag       = (int*)p;           p += sizeof(int);
    // zero region: bucketCount[NBUK] + stats[3 layers][2][D]
    char* zbase     = p;
    int* bucketCount= (int*)p;           p += NBUK * sizeof(int);
    float* stats    = (float*)p;         p += (size_t)L_LAYERS * 2 * D * sizeof(float);
    size_t zbytes   = (size_t)(p - zbase);

    detect_i64_kernel<<<1, 256, 0, stream>>>((const int*)ei, flag);
    hipMemsetAsync(zbase, 0, zbytes, stream);

    // One-time: weights to MFMA bf16 fragments; x to bf16.
    wperm_kernel<<<6 * 2048 / 256, 256, 0, stream>>>(W1, W2, Wp);
    cvt_kernel<<<(N_NODES * D / 4) / 256, 256, 0, stream>>>(x, Xb);

    // CSR build: bucket-partitioned (all scatter LDS/L2-local).
    count_kernel<<<NBIN_BLOCKS, 256, 0, stream>>>(ei, flag, bucketCount);
    bucket_scan_kernel<<<1, 256, 0, stream>>>(bucketCount, bucketBase, bucketCursor);
    bin_kernel<<<NBIN_BLOCKS, 256, 0, stream>>>(ei, flag, bucketCursor, binned);
    csr_build_kernel<<<NBUK, 256, 0, stream>>>(binned, bucketBase, rowptr, csr);

    const int gemmGrid = (N_NODES + 63) / 64;
    for (int l = 0; l < L_LAYERS; l++) {
        int fin = (l == L_LAYERS - 1) ? 1 : 0;
        float* gsum = stats + (size_t)l * 2 * D;
        float* gsq  = gsum + D;

        gather_prep_kernel<<<(N_NODES + 3) / 4, 256, 0, stream>>>(
            Xb, rowptr, csr, epsArr, l, B16);
        gemm1_mfma_kernel<<<gemmGrid, 256, 0, stream>>>(
            (const short*)B16, Wp + (size_t)l * D * D, b1 + (size_t)l * D,
            H16, gsum, gsq);
        gemm2_mfma_kernel<<<gemmGrid, 256, 0, stream>>>(
            H16, gsum, gsq, gamma + (size_t)l * D, beta + (size_t)l * D,
            Wp + (size_t)(3 + l) * D * D, b2 + (size_t)l * D,
            out, Xb, fin);
    }
}